// Round 11
// baseline (2524.375 us; speedup 1.0000x reference)
//
#include <hip/hip_runtime.h>
#include <math.h>

// Griffin-Lim inversion, fused bf16-3-term MFMA edition, M-tile=32, v2:
// register-prefetch pipelined B-streams (1-deep, unrolled K-loops) and
// conflict-free epilogue tr tile (split halves).  v = h+m+l (bf16 x3,
// exact to 2^-26); 6 MFMAs per product.  S lives in LDS (48 KB);
// 66 KB LDS total -> 2 blocks/CU.  FR ping-pongs across dispatches.

#define B_SZ 128
#define NFRM 256
#define BINS 128
#define NFFT 254
#define OUTL 16574
#define AUD  16384
#define GL_ITERS 50
#define MAXV 69.37411499023438f
#define PI2f 6.2831853071795864f

typedef __attribute__((ext_vector_type(8))) short short8;
typedef __attribute__((ext_vector_type(4))) short short4v;
typedef __attribute__((ext_vector_type(4))) float f32x4;

__device__ __forceinline__ unsigned short f2bf(float f) {     // RNE f32->bf16
  unsigned u = __float_as_uint(f);
  return (unsigned short)((u + 0x7FFFu + ((u >> 16) & 1u)) >> 16);
}
__device__ __forceinline__ float bf2f(unsigned short h) {
  return __uint_as_float(((unsigned)h) << 16);
}
__device__ __forceinline__ void split3(float v, short* h, short* m, short* l) {
  unsigned short hh = f2bf(v);
  float r1 = v - bf2f(hh);
  unsigned short mm = f2bf(r1);
  float r2 = r1 - bf2f(mm);
  *h = (short)hh; *m = (short)mm; *l = (short)f2bf(r2);
}

// S-LDS swizzle: 16B chunk c of row r -> slot (c&~7)|((c^r^(r>>3))&7)
__device__ __forceinline__ int slotf(int c, int row) {
  return (c & ~7) | ((c ^ row ^ (row >> 3)) & 7);
}

#define MFMA6(ACC, AH, AM, AL, BH, BM, BL)                                   \
  ACC = __builtin_amdgcn_mfma_f32_16x16x32_bf16(AH, BL, ACC, 0, 0, 0);       \
  ACC = __builtin_amdgcn_mfma_f32_16x16x32_bf16(AM, BM, ACC, 0, 0, 0);       \
  ACC = __builtin_amdgcn_mfma_f32_16x16x32_bf16(AL, BH, ACC, 0, 0, 0);       \
  ACC = __builtin_amdgcn_mfma_f32_16x16x32_bf16(AH, BM, ACC, 0, 0, 0);       \
  ACC = __builtin_amdgcn_mfma_f32_16x16x32_bf16(AM, BH, ACC, 0, 0, 0);       \
  ACC = __builtin_amdgcn_mfma_f32_16x16x32_bf16(AH, BH, ACC, 0, 0, 0);

// ---------------------------------------------------------------- tables ----
// Fragment order: tile (kc,nt): lane l elem j <- W[kc*32+(l>>4)*8+j][nt*16+(l&15)]
__global__ void tables_k(short* __restrict__ WfH, short* __restrict__ WfM,
                         short* __restrict__ WfL, short* __restrict__ WiH,
                         short* __restrict__ WiM, short* __restrict__ WiL,
                         unsigned* __restrict__ gmax) {
  int tid = blockIdx.x * blockDim.x + threadIdx.x;
  if (tid == 0) *gmax = 0u;
  if (tid >= 65536) return;
  int idx = tid;
  int j = idx & 7, l = (idx >> 3) & 63, nt = (idx >> 9) & 15, kc = idx >> 13;
  int krow = kc * 32 + ((l >> 4) << 3) + j;
  int ncol = (nt << 4) + (l & 15);
  float v1 = 0.f;
  if (krow < NFFT) {
    int kk = ncol >> 1;
    int m = (kk * krow) % NFFT;
    float ang = PI2f * (float)m / (float)NFFT;
    float wn = 0.5f - 0.5f * cosf(PI2f * (float)krow / (float)NFFT);
    v1 = wn * ((ncol & 1) ? -sinf(ang) : cosf(ang));
  }
  split3(v1, &WfH[idx], &WfM[idx], &WfL[idx]);
  float v2 = 0.f;
  if (ncol < NFFT) {
    int kk = krow >> 1;
    int m = (kk * ncol) % NFFT;
    float ang = PI2f * (float)m / (float)NFFT;
    float wn = 0.5f - 0.5f * cosf(PI2f * (float)ncol / (float)NFFT);
    float d = 0.f;
    int p = ncol & 63;
    for (int q = 0; q < 4; ++q) {
      int nn = p + 64 * q;
      if (nn < NFFT) { float w = 0.5f - 0.5f * cosf(PI2f * (float)nn / (float)NFFT); d += w * w; }
    }
    float sw = wn / d;
    float ak = (kk == 0 || kk == BINS - 1) ? 1.f : 2.f;
    v2 = sw * (ak / (float)NFFT) * ((krow & 1) ? -sinf(ang) : cosf(ang));
  }
  split3(v2, &WiH[idx], &WiM[idx], &WiL[idx]);
}

// ------------------------------------------------------------------- mag ----
__global__ void mag_k(const float* __restrict__ x, float* __restrict__ mag) {
  int i = blockIdx.x * 256 + threadIdx.x;          // 4194304 exact
  mag[i] = expf(5.f * (x[i] - 1.f)) * MAXV;
}

// ------------------------------------------------------ fused GL iteration --
// Block = (batch b, 32 frames from f0 = (blk&7)*32). 512 threads, 8 waves.
// Wave: 2 M-tiles x 2 N-tiles (ntg = wv*2+nt covers all 256 cols).
template <int FIRST>
__global__ __launch_bounds__(512) void iter_k(
    const float* __restrict__ FRsrc, float* __restrict__ FRdst,
    const float* __restrict__ mag,
    const short* __restrict__ WfH, const short* __restrict__ WfM,
    const short* __restrict__ WfL,
    const short* __restrict__ WiH, const short* __restrict__ WiM,
    const short* __restrict__ WiL) {
  __shared__ __align__(16) short SH[8192], SM[8192], SL[8192];   // 48 KB
  __shared__ __align__(16) char scratch[16896];                  // wfs | trA/trB
  short* wfsH = (short*)scratch;                   // 2240 shorts each
  short* wfsM = wfsH + 2240;
  short* wfsL = wfsM + 2240;
  float* trA = (float*)scratch;                    // 16 x 132 f32 (cols 8c+0..3)
  float* trB = trA + 2112;                         // 16 x 132 f32 (cols 8c+4..7)

  int blk = blockIdx.x;
  int b = blk >> 3, f0 = (blk & 7) << 5;
  int tid = threadIdx.x, lane = tid & 63, wv = tid >> 6;
  int fgl = b * NFRM + f0;
  int ntg0 = (wv << 1), ntg1 = ntg0 + 1;

  short8 g2h[2][2], g2m[2][2], g2l[2][2];          // gemm2 B double-buffer

  if (FIRST) {
    // S0 = (mag, 0), split3, swizzled into LDS
    int row = tid >> 4;                            // 0..31
#pragma unroll
    for (int q = 0; q < 2; ++q) {
      int c = ((tid & 15) << 1) + q;               // chunk 0..31
      float4 mg = *(const float4*)&mag[((size_t)(fgl + row) << 7) + (c << 2)];
      short h[8] __attribute__((aligned(16))), m[8] __attribute__((aligned(16))),
            l[8] __attribute__((aligned(16)));
#pragma unroll
      for (int u = 0; u < 4; ++u) {
        split3(((const float*)&mg)[u], &h[2 * u], &m[2 * u], &l[2 * u]);
        h[2 * u + 1] = 0; m[2 * u + 1] = 0; l[2 * u + 1] = 0;
      }
      int p = (row << 8) + (slotf(c, row) << 3);
      *(short8*)&SH[p] = *(const short8*)h;
      *(short8*)&SM[p] = *(const short8*)m;
      *(short8*)&SL[p] = *(const short8*)l;
    }
    {  // preload gemm2 B kc=0
      size_t o0 = (((size_t)ntg0 << 6) + lane) << 3;
      size_t o1 = (((size_t)ntg1 << 6) + lane) << 3;
      g2h[0][0] = *(const short8*)(WiH + o0); g2h[0][1] = *(const short8*)(WiH + o1);
      g2m[0][0] = *(const short8*)(WiM + o0); g2m[0][1] = *(const short8*)(WiM + o1);
      g2l[0][0] = *(const short8*)(WiL + o0); g2l[0][1] = *(const short8*)(WiL + o1);
    }
  } else {
    short8 g1h[2][2], g1m[2][2], g1l[2][2];        // gemm1 B double-buffer
    {  // preload gemm1 B kc=0 (overlaps with OA below)
      size_t o0 = (((size_t)ntg0 << 6) + lane) << 3;
      size_t o1 = (((size_t)ntg1 << 6) + lane) << 3;
      g1h[0][0] = *(const short8*)(WfH + o0); g1h[0][1] = *(const short8*)(WfH + o1);
      g1m[0][0] = *(const short8*)(WfM + o0); g1m[0][1] = *(const short8*)(WfM + o1);
      g1l[0][0] = *(const short8*)(WfL + o0); g1l[0][1] = *(const short8*)(WfL + o1);
    }

    const float* FRb = FRsrc + ((size_t)b << 16);
    // vectorized fused overlap-add -> split3 -> swizzled wfs (2238 samples)
    for (int i4 = tid; i4 < 560; i4 += 512) {
      int i = i4 << 2;
      int t = (f0 << 6) + i;
      int ft = t >> 6, cb = t & 63;
      float4 s = make_float4(0.f, 0.f, 0.f, 0.f);
#pragma unroll
      for (int d = 3; d >= 0; --d) {               // ascending f; extras exact 0
        int f = ft - d;
        if (f >= 0 && f <= 255) {
          float4 v = *(const float4*)&FRb[(f << 8) + cb + (d << 6)];
          s.x += v.x; s.y += v.y; s.z += v.z; s.w += v.w;
        }
      }
      if (i == 2236) { s.z = 0.f; s.w = 0.f; }     // pad samples 2238/2239
      short hh[4] __attribute__((aligned(8))), mm[4] __attribute__((aligned(8))),
            ll[4] __attribute__((aligned(8)));
      split3(s.x, &hh[0], &mm[0], &ll[0]);
      split3(s.y, &hh[1], &mm[1], &ll[1]);
      split3(s.z, &hh[2], &mm[2], &ll[2]);
      split3(s.w, &hh[3], &mm[3], &ll[3]);
      int q = i >> 3;
      int qs = (q & ~7) | ((q ^ (q >> 3)) & 7);
      int p = (qs << 3) | (i & 7);
      *(short4v*)&wfsH[p] = *(const short4v*)hh;
      *(short4v*)&wfsM[p] = *(const short4v*)mm;
      *(short4v*)&wfsL[p] = *(const short4v*)ll;
    }

    f32x4 acc1[2][2];
#pragma unroll
    for (int i = 0; i < 2; ++i) { acc1[i][0] = (f32x4){0,0,0,0}; acc1[i][1] = (f32x4){0,0,0,0}; }

    __syncthreads();                               // wfs ready

    // gemm1: X = A(wf) x Wf — B register-pipelined 1 kc ahead, no barriers
#pragma unroll
    for (int kc = 0; kc < 8; ++kc) {
      const int cur = kc & 1, nxt = cur ^ 1;
      if (kc < 7) {
        size_t o0 = (((size_t)(((kc + 1) << 4) + ntg0) << 6) + lane) << 3;
        size_t o1 = (((size_t)(((kc + 1) << 4) + ntg1) << 6) + lane) << 3;
        g1h[nxt][0] = *(const short8*)(WfH + o0); g1h[nxt][1] = *(const short8*)(WfH + o1);
        g1m[nxt][0] = *(const short8*)(WfM + o0); g1m[nxt][1] = *(const short8*)(WfM + o1);
        g1l[nxt][0] = *(const short8*)(WfL + o0); g1l[nxt][1] = *(const short8*)(WfL + o1);
      }
      short8 Ah[2], Am[2], Al[2];
#pragma unroll
      for (int mt = 0; mt < 2; ++mt) {
        int frame = (mt << 4) + (lane & 15);
        int q = (frame << 3) + (kc << 2) + (lane >> 4);
        int qs = (q & ~7) | ((q ^ (q >> 3)) & 7);
        Ah[mt] = *(const short8*)&wfsH[qs << 3];
        Am[mt] = *(const short8*)&wfsM[qs << 3];
        Al[mt] = *(const short8*)&wfsL[qs << 3];
      }
#pragma unroll
      for (int nt = 0; nt < 2; ++nt)
#pragma unroll
        for (int mt = 0; mt < 2; ++mt) {
          MFMA6(acc1[mt][nt], Ah[mt], Am[mt], Al[mt], g1h[cur][nt], g1m[cur][nt], g1l[cur][nt])
        }
    }

    {  // preload gemm2 B kc=0 (hides under epilogue)
      size_t o0 = (((size_t)ntg0 << 6) + lane) << 3;
      size_t o1 = (((size_t)ntg1 << 6) + lane) << 3;
      g2h[0][0] = *(const short8*)(WiH + o0); g2h[0][1] = *(const short8*)(WiH + o1);
      g2m[0][0] = *(const short8*)(WiM + o0); g2m[0][1] = *(const short8*)(WiM + o1);
      g2l[0][0] = *(const short8*)(WiL + o0); g2l[0][1] = *(const short8*)(WiL + o1);
    }

    // epilogue: 2 phases through split tr tiles (alias dead wfs);
    // spec = mag*X/|X|; split3; vectorized 16B S writes.
    for (int mtg = 0; mtg < 2; ++mtg) {
      __syncthreads();                             // scratch free
#pragma unroll
      for (int nt = 0; nt < 2; ++nt) {
        int col = (((wv << 1) + nt) << 4) | (lane & 15);
        int cc = col >> 3, hb = (col >> 2) & 1, w = col & 3;
        float* th = hb ? trB : trA;
        int base = (cc << 2) + w;
#pragma unroll
        for (int r = 0; r < 4; ++r) {
          int row16 = ((lane >> 4) << 2) + r;
          th[row16 * 132 + base] = acc1[mtg][nt][r];
        }
      }
      __syncthreads();
      {
        int trow = tid >> 5;                       // 0..15
        int c = tid & 31;                          // chunk
        float4 va = *(const float4*)&trA[trow * 132 + (c << 2)];  // cols 8c+0..3
        float4 vb = *(const float4*)&trB[trow * 132 + (c << 2)];  // cols 8c+4..7
        int lrow = (mtg << 4) + trow;              // 0..31
        int srow = fgl + lrow;
        float4 xm = *(const float4*)&mag[((size_t)srow << 7) + (c << 2)];
        float vv[8] = {va.x, va.y, va.z, va.w, vb.x, vb.y, vb.z, vb.w};
        short hh[8] __attribute__((aligned(16))), mm[8] __attribute__((aligned(16))),
              ll[8] __attribute__((aligned(16)));
#pragma unroll
        for (int pq = 0; pq < 4; ++pq) {
          float mg = ((const float*)&xm)[pq];
          float re = vv[2 * pq], im = vv[2 * pq + 1];
          float s2 = re * re + im * im;
          float oe, oo;
          if (s2 == 0.f) { oe = mg; oo = 0.f; }    // angle(0)=0
          else { float rr = mg * rsqrtf(s2); oe = re * rr; oo = im * rr; }
          split3(oe, &hh[2 * pq], &mm[2 * pq], &ll[2 * pq]);
          split3(oo, &hh[2 * pq + 1], &mm[2 * pq + 1], &ll[2 * pq + 1]);
        }
        int p = (lrow << 8) + (slotf(c, lrow) << 3);
        *(short8*)&SH[p] = *(const short8*)hh;
        *(short8*)&SM[p] = *(const short8*)mm;
        *(short8*)&SL[p] = *(const short8*)ll;
      }
    }
  }

  f32x4 acc2[2][2];
#pragma unroll
  for (int i = 0; i < 2; ++i) { acc2[i][0] = (f32x4){0,0,0,0}; acc2[i][1] = (f32x4){0,0,0,0}; }

  __syncthreads();                                 // S_lds ready

  // gemm2: FR = S x Wi — B register-pipelined 1 kc ahead, no barriers
#pragma unroll
  for (int kc = 0; kc < 8; ++kc) {
    const int cur = kc & 1, nxt = cur ^ 1;
    if (kc < 7) {
      size_t o0 = (((size_t)(((kc + 1) << 4) + ntg0) << 6) + lane) << 3;
      size_t o1 = (((size_t)(((kc + 1) << 4) + ntg1) << 6) + lane) << 3;
      g2h[nxt][0] = *(const short8*)(WiH + o0); g2h[nxt][1] = *(const short8*)(WiH + o1);
      g2m[nxt][0] = *(const short8*)(WiM + o0); g2m[nxt][1] = *(const short8*)(WiM + o1);
      g2l[nxt][0] = *(const short8*)(WiL + o0); g2l[nxt][1] = *(const short8*)(WiL + o1);
    }
#pragma unroll
    for (int mt = 0; mt < 2; ++mt) {
      int rl = (mt << 4) + (lane & 15);
      int c = (kc << 2) + (lane >> 4);
      int base = (rl << 8) + (slotf(c, rl) << 3);
      short8 Ah = *(const short8*)&SH[base];
      short8 Am = *(const short8*)&SM[base];
      short8 Al = *(const short8*)&SL[base];
#pragma unroll
      for (int nt = 0; nt < 2; ++nt) {
        MFMA6(acc2[mt][nt], Ah, Am, Al, g2h[cur][nt], g2m[cur][nt], g2l[cur][nt])
      }
    }
  }

  float* FRo = FRdst + ((size_t)b << 16) + ((size_t)f0 << 8);
#pragma unroll
  for (int mt = 0; mt < 2; ++mt)
#pragma unroll
    for (int nt = 0; nt < 2; ++nt) {
      int col = (((wv << 1) + nt) << 4) | (lane & 15);
#pragma unroll
      for (int r = 0; r < 4; ++r) {
        int row = (mt << 4) + ((lane >> 4) << 2) + r;
        FRo[((size_t)row << 8) + col] = acc2[mt][nt][r];
      }
    }
}

// ------------------------------------------------- reductions (OA fused) ----
__global__ void redmax_k(const float* __restrict__ FR, unsigned* __restrict__ gmax) {
  __shared__ float red[16];
  int b = blockIdx.x;
  const float* FRb = FR + ((size_t)b << 16);
  float v = 0.f;
  for (int t = threadIdx.x; t < OUTL; t += 1024) {
    int f_hi = t >> 6; if (f_hi > NFRM - 1) f_hi = NFRM - 1;
    int f_lo = (t >= NFFT) ? (((t - NFFT) >> 6) + 1) : 0;
    float s = 0.f;
    for (int f = f_lo; f <= f_hi; ++f) s += FRb[(f << 8) + t - (f << 6)];
    v = fmaxf(v, fabsf(s));
  }
#pragma unroll
  for (int o = 32; o > 0; o >>= 1) v = fmaxf(v, __shfl_xor(v, o, 64));
  if ((threadIdx.x & 63) == 0) red[threadIdx.x >> 6] = v;
  __syncthreads();
  if (threadIdx.x < 16) {
    v = red[threadIdx.x];
#pragma unroll
    for (int o = 8; o > 0; o >>= 1) v = fmaxf(v, __shfl_xor(v, o, 16));
    if (threadIdx.x == 0) atomicMax(gmax, __float_as_uint(v));
  }
}

__global__ void out_k(const float* __restrict__ FR, const unsigned* __restrict__ gmax,
                      float* __restrict__ out) {
  int b = blockIdx.y, t = blockIdx.x * 256 + threadIdx.x;   // t < 16384
  const float* FRb = FR + ((size_t)b << 16);
  int f_hi = t >> 6; if (f_hi > NFRM - 1) f_hi = NFRM - 1;
  int f_lo = (t >= NFFT) ? (((t - NFFT) >> 6) + 1) : 0;
  float s = 0.f;
  for (int f = f_lo; f <= f_hi; ++f) s += FRb[(f << 8) + t - (f << 6)];
  float g = __uint_as_float(*gmax);
  out[(size_t)b * AUD + t] = s / g;
}

// ---------------------------------------------------------------- launch ----
extern "C" void kernel_launch(void* const* d_in, const int* in_sizes, int n_in,
                              void* d_out, int out_size, void* d_ws, size_t ws_size,
                              hipStream_t stream) {
  const float* x = (const float*)d_in[0];

  float* FR0 = (float*)d_ws;                       // 8,388,608 f
  float* FR1 = FR0 + 8388608;                      // 8,388,608 f
  float* mag = FR1 + 8388608;                      // 4,194,304 f
  short* WfH = (short*)(mag + 4194304);            // 65536 sh each
  short* WfM = WfH + 65536;
  short* WfL = WfM + 65536;
  short* WiH = WfL + 65536;
  short* WiM = WiH + 65536;
  short* WiL = WiM + 65536;
  unsigned* gmax = (unsigned*)(WiL + 65536);       // ~85 MB total

  mag_k<<<16384, 256, 0, stream>>>(x, mag);
  tables_k<<<256, 256, 0, stream>>>(WfH, WfM, WfL, WiH, WiM, WiL, gmax);

  // initial istft of (mag, 0) -> FR0
  iter_k<1><<<1024, 512, 0, stream>>>(FR1, FR0, mag, WfH, WfM, WfL, WiH, WiM, WiL);

  float* bufs[2] = {FR0, FR1};
  for (int it = 0; it < GL_ITERS; ++it) {
    iter_k<0><<<1024, 512, 0, stream>>>(bufs[it & 1], bufs[(it + 1) & 1], mag,
                                        WfH, WfM, WfL, WiH, WiM, WiL);
  }
  // 50 even -> final waveform frames in FR0

  redmax_k<<<B_SZ, 1024, 0, stream>>>(FR0, gmax);
  out_k<<<dim3(64, B_SZ), 256, 0, stream>>>(FR0, gmax, (float*)d_out);
}

// Round 13
// 2189.784 us; speedup vs baseline: 1.1528x; 1.1528x over previous
//
#include <hip/hip_runtime.h>
#include <math.h>

// Griffin-Lim inversion, fused bf16-3-term MFMA, M-tile=32, HALF-FOLDED:
// gemm1 (STFT) identical to the validated round-10 form (K=256, interleaved
// spec cols, bit-identical X / spec values).  gemm2 (iSTFT) folded via the
// n <-> 254-n symmetry: Sre/Sim stored separately, two K=128 half-GEMMs
// (C = Sre x CI, S_ = Sim x SI), unfold fr[n]=swin[n](C+S_),
// fr[254-n]=swin[254-n](C-S_).  Halves gemm2 MFMA + table bytes.

#define B_SZ 128
#define NFRM 256
#define BINS 128
#define NFFT 254
#define OUTL 16574
#define AUD  16384
#define GL_ITERS 50
#define MAXV 69.37411499023438f
#define PI2f 6.2831853071795864f

typedef __attribute__((ext_vector_type(8))) short short8;
typedef __attribute__((ext_vector_type(4))) short short4v;
typedef __attribute__((ext_vector_type(4))) float f32x4;

__device__ __forceinline__ unsigned short f2bf(float f) {     // RNE f32->bf16
  unsigned u = __float_as_uint(f);
  return (unsigned short)((u + 0x7FFFu + ((u >> 16) & 1u)) >> 16);
}
__device__ __forceinline__ float bf2f(unsigned short h) {
  return __uint_as_float(((unsigned)h) << 16);
}
__device__ __forceinline__ void split3(float v, short* h, short* m, short* l) {
  unsigned short hh = f2bf(v);
  float r1 = v - bf2f(hh);
  unsigned short mm = f2bf(r1);
  float r2 = r1 - bf2f(mm);
  *h = (short)hh; *m = (short)mm; *l = (short)f2bf(r2);
}
// 16B chunk c of row r -> slot (c&~7)|((c^r^(r>>3))&7)  (bijective per 8-group)
__device__ __forceinline__ int slotf(int c, int row) {
  return (c & ~7) | ((c ^ row ^ (row >> 3)) & 7);
}

#define MFMA6(ACC, AH, AM, AL, BH, BM, BL)                                   \
  ACC = __builtin_amdgcn_mfma_f32_16x16x32_bf16(AH, BL, ACC, 0, 0, 0);       \
  ACC = __builtin_amdgcn_mfma_f32_16x16x32_bf16(AM, BM, ACC, 0, 0, 0);       \
  ACC = __builtin_amdgcn_mfma_f32_16x16x32_bf16(AL, BH, ACC, 0, 0, 0);       \
  ACC = __builtin_amdgcn_mfma_f32_16x16x32_bf16(AH, BM, ACC, 0, 0, 0);       \
  ACC = __builtin_amdgcn_mfma_f32_16x16x32_bf16(AM, BH, ACC, 0, 0, 0);       \
  ACC = __builtin_amdgcn_mfma_f32_16x16x32_bf16(AH, BH, ACC, 0, 0, 0);

// ---------------------------------------------------------------- tables ----
// Wf (forward, unfolded, round-10 layout): 65536 entries, fragment order
//   tile (kc,nt): lane l elem j <- Wf[kc*32+(l>>4)*8+j][nt*16+(l&15)], nt 0..15.
// CI/SI (inverse, folded): 16384 entries, krow=bin k (K-dim), ncol=sample n,
//   CI[k][n]=(ak/254)cos(2pi k n/254), SI[k][n]=-(ak/254)sin(2pi k n/254).
__global__ void tables_k(short* __restrict__ WfH, short* __restrict__ WfM,
                         short* __restrict__ WfL, short* __restrict__ CI,
                         short* __restrict__ SI, float* __restrict__ swin,
                         unsigned* __restrict__ gmax) {
  int tid = blockIdx.x * blockDim.x + threadIdx.x;
  if (tid == 0) *gmax = 0u;
  if (tid < 256) {
    float v = 0.f;
    if (tid < NFFT) {
      float wn = 0.5f - 0.5f * cosf(PI2f * (float)tid / (float)NFFT);
      float d = 0.f;
      int p = tid & 63;
      for (int q = 0; q < 4; ++q) {
        int nn = p + 64 * q;
        if (nn < NFFT) { float w = 0.5f - 0.5f * cosf(PI2f * (float)nn / (float)NFFT); d += w * w; }
      }
      v = wn / d;
    }
    swin[tid] = v;
  }
  if (tid < 65536) {
    int j = tid & 7, l = (tid >> 3) & 63, nt = (tid >> 9) & 15, kc = tid >> 13;
    int krow = kc * 32 + ((l >> 4) << 3) + j;        // sample n 0..255
    int ncol = (nt << 4) + (l & 15);                 // spec col 0..255
    float v1 = 0.f;
    if (krow < NFFT) {
      int kk = ncol >> 1;
      int m = (kk * krow) % NFFT;
      float ang = PI2f * (float)m / (float)NFFT;
      float wn = 0.5f - 0.5f * cosf(PI2f * (float)krow / (float)NFFT);
      v1 = wn * ((ncol & 1) ? -sinf(ang) : cosf(ang));
    }
    split3(v1, &WfH[tid], &WfM[tid], &WfL[tid]);
  }
  if (tid < 16384) {
    int j = tid & 7, l = (tid >> 3) & 63;
    int krow = (tid >> 12) * 32 + ((l >> 4) << 3) + j;   // bin k 0..127
    int ncol = (((tid >> 9) & 7) << 4) + (l & 15);       // sample n 0..127
    int m = (krow * ncol) % NFFT;
    float ang = PI2f * (float)m / (float)NFFT;
    float sc = ((krow == 0 || krow == BINS - 1) ? 1.f : 2.f) / (float)NFFT;
    split3(sc * cosf(ang), &CI[tid], &CI[16384 + tid], &CI[32768 + tid]);
    split3(-sc * sinf(ang), &SI[tid], &SI[16384 + tid], &SI[32768 + tid]);
  }
}

// ------------------------------------------------------------------- mag ----
__global__ void mag_k(const float* __restrict__ x, float* __restrict__ mag) {
  int i = blockIdx.x * 256 + threadIdx.x;          // 4194304 exact
  mag[i] = expf(5.f * (x[i] - 1.f)) * MAXV;
}

// ------------------------------------------------------ fused GL iteration --
// Block = (batch b, 32 frames from f0=(blk&7)*32). 512 threads, 8 waves.
// Y (48 KB): Sre {H,M,L} at 0/4096/8192, Sim {H,M,L} at 12288/16384/20480,
// each [32 rows][128 bins] with slotf chunk swizzle.
template <int FIRST>
__global__ __launch_bounds__(512) void iter_k(
    const float* __restrict__ FRsrc, float* __restrict__ FRdst,
    const float* __restrict__ mag, const float* __restrict__ swin,
    const short* __restrict__ WfH, const short* __restrict__ WfM,
    const short* __restrict__ WfL,
    const short* __restrict__ CI, const short* __restrict__ SI) {
  __shared__ __align__(16) short Y[24576];         // 48 KB (Sre/Sim)
  __shared__ __align__(16) char scratch[16896];    // wfs | trA/trB
  short* wfsH = (short*)scratch;                   // 2240 shorts each
  short* wfsM = wfsH + 2240;
  short* wfsL = wfsM + 2240;
  float* trA = (float*)scratch;                    // 16 x 132 f32 (cols 8c+0..3)
  float* trB = trA + 2112;                         // 16 x 132 f32 (cols 8c+4..7)

  int blk = blockIdx.x;
  int b = blk >> 3, f0 = (blk & 7) << 5;
  int tid = threadIdx.x, lane = tid & 63, wv = tid >> 6;
  int fgl = b * NFRM + f0;

  if (FIRST) {
    // S0 = (mag, 0): Sre = split3(mag), Sim = 0
    int row = tid >> 4, q = tid & 15;              // row 0..31, bin-octet 0..15
    int srow = fgl + row;
    float4 m0 = *(const float4*)&mag[((size_t)srow << 7) + (q << 3)];
    float4 m1 = *(const float4*)&mag[((size_t)srow << 7) + (q << 3) + 4];
    float mv[8] = {m0.x, m0.y, m0.z, m0.w, m1.x, m1.y, m1.z, m1.w};
    short h[8] __attribute__((aligned(16))), m[8] __attribute__((aligned(16))),
          l[8] __attribute__((aligned(16))), z[8] __attribute__((aligned(16)));
#pragma unroll
    for (int e = 0; e < 8; ++e) { split3(mv[e], &h[e], &m[e], &l[e]); z[e] = 0; }
    int off = (row << 7) + (slotf(q, row) << 3);
    *(short8*)&Y[off]         = *(const short8*)h;
    *(short8*)&Y[4096 + off]  = *(const short8*)m;
    *(short8*)&Y[8192 + off]  = *(const short8*)l;
    *(short8*)&Y[12288 + off] = *(const short8*)z;
    *(short8*)&Y[16384 + off] = *(const short8*)z;
    *(short8*)&Y[20480 + off] = *(const short8*)z;
  } else {
    const float* FRb = FRsrc + ((size_t)b << 16);
    // vectorized fused overlap-add -> split3 -> swizzled wfs (round-10 exact)
    for (int i4 = tid; i4 < 560; i4 += 512) {
      int i = i4 << 2;
      int t = (f0 << 6) + i;
      int ft = t >> 6, cb = t & 63;
      float4 s = make_float4(0.f, 0.f, 0.f, 0.f);
#pragma unroll
      for (int d = 3; d >= 0; --d) {               // ascending f; extras exact 0
        int f = ft - d;
        if (f >= 0 && f <= 255) {
          float4 v = *(const float4*)&FRb[(f << 8) + cb + (d << 6)];
          s.x += v.x; s.y += v.y; s.z += v.z; s.w += v.w;
        }
      }
      if (i == 2236) { s.z = 0.f; s.w = 0.f; }     // pad samples 2238/2239
      short hh[4] __attribute__((aligned(8))), mm[4] __attribute__((aligned(8))),
            ll[4] __attribute__((aligned(8)));
      split3(s.x, &hh[0], &mm[0], &ll[0]);
      split3(s.y, &hh[1], &mm[1], &ll[1]);
      split3(s.z, &hh[2], &mm[2], &ll[2]);
      split3(s.w, &hh[3], &mm[3], &ll[3]);
      int q = i >> 3;
      int qs = (q & ~7) | ((q ^ (q >> 3)) & 7);
      int p = (qs << 3) | (i & 7);
      *(short4v*)&wfsH[p] = *(const short4v*)hh;
      *(short4v*)&wfsM[p] = *(const short4v*)mm;
      *(short4v*)&wfsL[p] = *(const short4v*)ll;
    }

    f32x4 acc1[2][2];
#pragma unroll
    for (int i = 0; i < 2; ++i) { acc1[i][0] = (f32x4){0,0,0,0}; acc1[i][1] = (f32x4){0,0,0,0}; }

    __syncthreads();                               // wfs ready

    // gemm1 (round-10 exact): X = A(wf) x Wf, K=256, B streamed from L2
    for (int kc = 0; kc < 8; ++kc) {
      short8 Ah[2], Am[2], Al[2];
#pragma unroll
      for (int mt = 0; mt < 2; ++mt) {
        int frame = (mt << 4) + (lane & 15);
        int q = (frame << 3) + (kc << 2) + (lane >> 4);
        int qs = (q & ~7) | ((q ^ (q >> 3)) & 7);
        Ah[mt] = *(const short8*)&wfsH[qs << 3];
        Am[mt] = *(const short8*)&wfsM[qs << 3];
        Al[mt] = *(const short8*)&wfsL[qs << 3];
      }
#pragma unroll
      for (int nt = 0; nt < 2; ++nt) {
        int ntg = (wv << 1) + nt;
        size_t off = (((size_t)((kc << 4) + ntg) << 6) + lane) << 3;
        short8 bh = *(const short8*)(WfH + off);
        short8 bm = *(const short8*)(WfM + off);
        short8 bl = *(const short8*)(WfL + off);
#pragma unroll
        for (int mt = 0; mt < 2; ++mt) {
          MFMA6(acc1[mt][nt], Ah[mt], Am[mt], Al[mt], bh, bm, bl)
        }
      }
    }

    // epilogue (round-10 tr-bounce): spec = mag*X/|X|; NEW: write Sre/Sim
    for (int mtg = 0; mtg < 2; ++mtg) {
      __syncthreads();                             // scratch free
#pragma unroll
      for (int nt = 0; nt < 2; ++nt) {
        int col = (((wv << 1) + nt) << 4) | (lane & 15);
        int cc = col >> 3, hb = (col >> 2) & 1, w = col & 3;
        float* th = hb ? trB : trA;
        int base = (cc << 2) + w;
#pragma unroll
        for (int r = 0; r < 4; ++r) {
          int row16 = ((lane >> 4) << 2) + r;
          th[row16 * 132 + base] = acc1[mtg][nt][r];
        }
      }
      __syncthreads();
      {
        int trow = tid >> 5;                       // 0..15
        int c = tid & 31;                          // 8-col chunk = 4 bins 4c..4c+3
        float4 va = *(const float4*)&trA[trow * 132 + (c << 2)];  // cols 8c+0..3
        float4 vb = *(const float4*)&trB[trow * 132 + (c << 2)];  // cols 8c+4..7
        int lrow = (mtg << 4) + trow;              // 0..31
        int srow = fgl + lrow;
        float4 xm = *(const float4*)&mag[((size_t)srow << 7) + (c << 2)];
        float vv[8] = {va.x, va.y, va.z, va.w, vb.x, vb.y, vb.z, vb.w};
        short reh[4] __attribute__((aligned(8))), rem[4] __attribute__((aligned(8))),
              rel[4] __attribute__((aligned(8))), imh[4] __attribute__((aligned(8))),
              imm[4] __attribute__((aligned(8))), iml[4] __attribute__((aligned(8)));
#pragma unroll
        for (int pq = 0; pq < 4; ++pq) {
          float mg = ((const float*)&xm)[pq];
          float re = vv[2 * pq], im = vv[2 * pq + 1];
          float s2 = re * re + im * im;
          float ore, oim;
          if (s2 == 0.f) { ore = mg; oim = 0.f; }  // angle(0)=0
          else { float rr = mg * rsqrtf(s2); ore = re * rr; oim = im * rr; }
          split3(ore, &reh[pq], &rem[pq], &rel[pq]);
          split3(oim, &imh[pq], &imm[pq], &iml[pq]);
        }
        int c2 = c >> 1, half = (c & 1) << 2;      // bins 4c..4c+3 in [32][128]
        int off2 = (lrow << 7) + (slotf(c2, lrow) << 3) + half;
        *(short4v*)&Y[off2]         = *(const short4v*)reh;
        *(short4v*)&Y[4096 + off2]  = *(const short4v*)rem;
        *(short4v*)&Y[8192 + off2]  = *(const short4v*)rel;
        *(short4v*)&Y[12288 + off2] = *(const short4v*)imh;
        *(short4v*)&Y[16384 + off2] = *(const short4v*)imm;
        *(short4v*)&Y[20480 + off2] = *(const short4v*)iml;
      }
    }
  }

  f32x4 aC[2], aS[2];
#pragma unroll
  for (int i = 0; i < 2; ++i) { aC[i] = (f32x4){0,0,0,0}; aS[i] = (f32x4){0,0,0,0}; }

  __syncthreads();                                 // Sre/Sim ready

  // gemm2 (folded): C = Sre x CI, S_ = Sim x SI, K=128 each, no barriers
  for (int kc = 0; kc < 4; ++kc) {
    short8 ReH[2], ReM[2], ReL[2], ImH[2], ImM[2], ImL[2];
#pragma unroll
    for (int mt = 0; mt < 2; ++mt) {
      int rl = (mt << 4) + (lane & 15);
      int c = (kc << 2) + (lane >> 4);
      int off = (rl << 7) + (slotf(c, rl) << 3);
      ReH[mt] = *(const short8*)&Y[off];
      ReM[mt] = *(const short8*)&Y[4096 + off];
      ReL[mt] = *(const short8*)&Y[8192 + off];
      ImH[mt] = *(const short8*)&Y[12288 + off];
      ImM[mt] = *(const short8*)&Y[16384 + off];
      ImL[mt] = *(const short8*)&Y[20480 + off];
    }
    size_t flat = (((size_t)((kc << 3) + wv) << 6) + lane) << 3;
    short8 ch = *(const short8*)(CI + flat);
    short8 cm = *(const short8*)(CI + 16384 + flat);
    short8 cl = *(const short8*)(CI + 32768 + flat);
    short8 sh = *(const short8*)(SI + flat);
    short8 sm = *(const short8*)(SI + 16384 + flat);
    short8 sl = *(const short8*)(SI + 32768 + flat);
#pragma unroll
    for (int mt = 0; mt < 2; ++mt) {
      MFMA6(aC[mt], ReH[mt], ReM[mt], ReL[mt], ch, cm, cl)
      MFMA6(aS[mt], ImH[mt], ImM[mt], ImL[mt], sh, sm, sl)
    }
  }

  // unfold: fr[n]=swin[n](C+S_), fr[254-n]=swin[254-n](C-S_)
  {
    int n = (wv << 4) + (lane & 15);               // 0..127
    float swn = swin[n];
    float swp = swin[254 - n];
    float* FRo = FRdst + ((size_t)b << 16) + ((size_t)f0 << 8);
#pragma unroll
    for (int mt = 0; mt < 2; ++mt)
#pragma unroll
      for (int r = 0; r < 4; ++r) {
        int row = (mt << 4) + ((lane >> 4) << 2) + r;
        float C = aC[mt][r], S_ = aS[mt][r];
        FRo[((size_t)row << 8) + n] = swn * (C + S_);
        if (n >= 1 && n <= 126) FRo[((size_t)row << 8) + 254 - n] = swp * (C - S_);
        if (n == 0) { FRo[((size_t)row << 8) + 254] = 0.f; FRo[((size_t)row << 8) + 255] = 0.f; }
      }
  }
}

// ------------------------------------------------- reductions (OA fused) ----
__global__ void redmax_k(const float* __restrict__ FR, unsigned* __restrict__ gmax) {
  __shared__ float red[16];
  int b = blockIdx.x;
  const float* FRb = FR + ((size_t)b << 16);
  float v = 0.f;
  for (int t = threadIdx.x; t < OUTL; t += 1024) {
    int f_hi = t >> 6; if (f_hi > NFRM - 1) f_hi = NFRM - 1;
    int f_lo = (t >= NFFT) ? (((t - NFFT) >> 6) + 1) : 0;
    float s = 0.f;
    for (int f = f_lo; f <= f_hi; ++f) s += FRb[(f << 8) + t - (f << 6)];
    v = fmaxf(v, fabsf(s));
  }
#pragma unroll
  for (int o = 32; o > 0; o >>= 1) v = fmaxf(v, __shfl_xor(v, o, 64));
  if ((threadIdx.x & 63) == 0) red[threadIdx.x >> 6] = v;
  __syncthreads();
  if (threadIdx.x < 16) {
    v = red[threadIdx.x];
#pragma unroll
    for (int o = 8; o > 0; o >>= 1) v = fmaxf(v, __shfl_xor(v, o, 16));
    if (threadIdx.x == 0) atomicMax(gmax, __float_as_uint(v));
  }
}

__global__ void out_k(const float* __restrict__ FR, const unsigned* __restrict__ gmax,
                      float* __restrict__ out) {
  int b = blockIdx.y, t = blockIdx.x * 256 + threadIdx.x;   // t < 16384
  const float* FRb = FR + ((size_t)b << 16);
  int f_hi = t >> 6; if (f_hi > NFRM - 1) f_hi = NFRM - 1;
  int f_lo = (t >= NFFT) ? (((t - NFFT) >> 6) + 1) : 0;
  float s = 0.f;
  for (int f = f_lo; f <= f_hi; ++f) s += FRb[(f << 8) + t - (f << 6)];
  float g = __uint_as_float(*gmax);
  out[(size_t)b * AUD + t] = s / g;
}

// ---------------------------------------------------------------- launch ----
extern "C" void kernel_launch(void* const* d_in, const int* in_sizes, int n_in,
                              void* d_out, int out_size, void* d_ws, size_t ws_size,
                              hipStream_t stream) {
  const float* x = (const float*)d_in[0];

  float* FR0 = (float*)d_ws;                       // 8,388,608 f
  float* FR1 = FR0 + 8388608;                      // 8,388,608 f
  float* mag = FR1 + 8388608;                      // 4,194,304 f
  short* WfH = (short*)(mag + 4194304);            // 65536 sh each
  short* WfM = WfH + 65536;
  short* WfL = WfM + 65536;
  short* CI  = WfL + 65536;                        // 49152 sh each
  short* SI  = CI + 49152;
  float* swin = (float*)(SI + 49152);              // 256 f
  unsigned* gmax = (unsigned*)(swin + 256);        // ~84.7 MB total

  mag_k<<<16384, 256, 0, stream>>>(x, mag);
  tables_k<<<256, 256, 0, stream>>>(WfH, WfM, WfL, CI, SI, swin, gmax);

  // initial istft of (mag, 0) -> FR0
  iter_k<1><<<1024, 512, 0, stream>>>(FR1, FR0, mag, swin, WfH, WfM, WfL, CI, SI);

  float* bufs[2] = {FR0, FR1};
  for (int it = 0; it < GL_ITERS; ++it) {
    iter_k<0><<<1024, 512, 0, stream>>>(bufs[it & 1], bufs[(it + 1) & 1], mag, swin,
                                        WfH, WfM, WfL, CI, SI);
  }
  // 50 even -> final waveform frames in FR0

  redmax_k<<<B_SZ, 1024, 0, stream>>>(FR0, gmax);
  out_k<<<dim3(64, B_SZ), 256, 0, stream>>>(FR0, gmax, (float*)d_out);
}

// Round 15
// 2112.312 us; speedup vs baseline: 1.1951x; 1.0367x over previous
//
#include <hip/hip_runtime.h>
#include <math.h>

// Griffin-Lim inversion, fused bf16-3-term MFMA, M-tile=32, HALF-FOLDED
// (round-13 validated math, bit-identical values) + schedule tweaks:
//   - s_setprio(1) around MFMA clusters (T5; waves are phase-diverse here)
//   - XCD-aware bijective blockIdx swizzle (T1; same-batch blocks co-XCD)
// gemm1 (STFT): K=256 unfolded, interleaved spec cols.  gemm2 (iSTFT):
// folded n<->254-n, two K=128 half-GEMMs + fp32 unfold with swin.

#define B_SZ 128
#define NFRM 256
#define BINS 128
#define NFFT 254
#define OUTL 16574
#define AUD  16384
#define GL_ITERS 50
#define MAXV 69.37411499023438f
#define PI2f 6.2831853071795864f

typedef __attribute__((ext_vector_type(8))) short short8;
typedef __attribute__((ext_vector_type(4))) short short4v;
typedef __attribute__((ext_vector_type(4))) float f32x4;

__device__ __forceinline__ unsigned short f2bf(float f) {     // RNE f32->bf16
  unsigned u = __float_as_uint(f);
  return (unsigned short)((u + 0x7FFFu + ((u >> 16) & 1u)) >> 16);
}
__device__ __forceinline__ float bf2f(unsigned short h) {
  return __uint_as_float(((unsigned)h) << 16);
}
__device__ __forceinline__ void split3(float v, short* h, short* m, short* l) {
  unsigned short hh = f2bf(v);
  float r1 = v - bf2f(hh);
  unsigned short mm = f2bf(r1);
  float r2 = r1 - bf2f(mm);
  *h = (short)hh; *m = (short)mm; *l = (short)f2bf(r2);
}
// 16B chunk c of row r -> slot (c&~7)|((c^r^(r>>3))&7)  (bijective per 8-group)
__device__ __forceinline__ int slotf(int c, int row) {
  return (c & ~7) | ((c ^ row ^ (row >> 3)) & 7);
}

#define MFMA6(ACC, AH, AM, AL, BH, BM, BL)                                   \
  ACC = __builtin_amdgcn_mfma_f32_16x16x32_bf16(AH, BL, ACC, 0, 0, 0);       \
  ACC = __builtin_amdgcn_mfma_f32_16x16x32_bf16(AM, BM, ACC, 0, 0, 0);       \
  ACC = __builtin_amdgcn_mfma_f32_16x16x32_bf16(AL, BH, ACC, 0, 0, 0);       \
  ACC = __builtin_amdgcn_mfma_f32_16x16x32_bf16(AH, BM, ACC, 0, 0, 0);       \
  ACC = __builtin_amdgcn_mfma_f32_16x16x32_bf16(AM, BH, ACC, 0, 0, 0);       \
  ACC = __builtin_amdgcn_mfma_f32_16x16x32_bf16(AH, BH, ACC, 0, 0, 0);

// ---------------------------------------------------------------- tables ----
__global__ void tables_k(short* __restrict__ WfH, short* __restrict__ WfM,
                         short* __restrict__ WfL, short* __restrict__ CI,
                         short* __restrict__ SI, float* __restrict__ swin,
                         unsigned* __restrict__ gmax) {
  int tid = blockIdx.x * blockDim.x + threadIdx.x;
  if (tid == 0) *gmax = 0u;
  if (tid < 256) {
    float v = 0.f;
    if (tid < NFFT) {
      float wn = 0.5f - 0.5f * cosf(PI2f * (float)tid / (float)NFFT);
      float d = 0.f;
      int p = tid & 63;
      for (int q = 0; q < 4; ++q) {
        int nn = p + 64 * q;
        if (nn < NFFT) { float w = 0.5f - 0.5f * cosf(PI2f * (float)nn / (float)NFFT); d += w * w; }
      }
      v = wn / d;
    }
    swin[tid] = v;
  }
  if (tid < 65536) {
    int j = tid & 7, l = (tid >> 3) & 63, nt = (tid >> 9) & 15, kc = tid >> 13;
    int krow = kc * 32 + ((l >> 4) << 3) + j;        // sample n 0..255
    int ncol = (nt << 4) + (l & 15);                 // spec col 0..255
    float v1 = 0.f;
    if (krow < NFFT) {
      int kk = ncol >> 1;
      int m = (kk * krow) % NFFT;
      float ang = PI2f * (float)m / (float)NFFT;
      float wn = 0.5f - 0.5f * cosf(PI2f * (float)krow / (float)NFFT);
      v1 = wn * ((ncol & 1) ? -sinf(ang) : cosf(ang));
    }
    split3(v1, &WfH[tid], &WfM[tid], &WfL[tid]);
  }
  if (tid < 16384) {
    int j = tid & 7, l = (tid >> 3) & 63;
    int krow = (tid >> 12) * 32 + ((l >> 4) << 3) + j;   // bin k 0..127
    int ncol = (((tid >> 9) & 7) << 4) + (l & 15);       // sample n 0..127
    int m = (krow * ncol) % NFFT;
    float ang = PI2f * (float)m / (float)NFFT;
    float sc = ((krow == 0 || krow == BINS - 1) ? 1.f : 2.f) / (float)NFFT;
    split3(sc * cosf(ang), &CI[tid], &CI[16384 + tid], &CI[32768 + tid]);
    split3(-sc * sinf(ang), &SI[tid], &SI[16384 + tid], &SI[32768 + tid]);
  }
}

// ------------------------------------------------------------------- mag ----
__global__ void mag_k(const float* __restrict__ x, float* __restrict__ mag) {
  int i = blockIdx.x * 256 + threadIdx.x;          // 4194304 exact
  mag[i] = expf(5.f * (x[i] - 1.f)) * MAXV;
}

// ------------------------------------------------------ fused GL iteration --
// Block (after XCD swizzle) = (batch b, 32 frames from f0=(blk&7)*32).
// 512 threads, 8 waves.  Y (48 KB): Sre {H,M,L} 0/4096/8192, Sim {H,M,L}
// 12288/16384/20480, each [32 rows][128 bins] slotf-swizzled.
template <int FIRST>
__global__ __launch_bounds__(512) void iter_k(
    const float* __restrict__ FRsrc, float* __restrict__ FRdst,
    const float* __restrict__ mag, const float* __restrict__ swin,
    const short* __restrict__ WfH, const short* __restrict__ WfM,
    const short* __restrict__ WfL,
    const short* __restrict__ CI, const short* __restrict__ SI) {
  __shared__ __align__(16) short Y[24576];         // 48 KB (Sre/Sim)
  __shared__ __align__(16) char scratch[16896];    // wfs | trA/trB
  short* wfsH = (short*)scratch;                   // 2240 shorts each
  short* wfsM = wfsH + 2240;
  short* wfsL = wfsM + 2240;
  float* trA = (float*)scratch;                    // 16 x 132 f32 (cols 8c+0..3)
  float* trB = trA + 2112;                         // 16 x 132 f32 (cols 8c+4..7)

  // T1: bijective XCD swizzle (1024 % 8 == 0): same-batch blocks co-XCD.
  int o = blockIdx.x;
  int blk = ((o & 7) << 7) + (o >> 3);
  int b = blk >> 3, f0 = (blk & 7) << 5;
  int tid = threadIdx.x, lane = tid & 63, wv = tid >> 6;
  int fgl = b * NFRM + f0;

  if (FIRST) {
    // S0 = (mag, 0): Sre = split3(mag), Sim = 0
    int row = tid >> 4, q = tid & 15;              // row 0..31, bin-octet 0..15
    int srow = fgl + row;
    float4 m0 = *(const float4*)&mag[((size_t)srow << 7) + (q << 3)];
    float4 m1 = *(const float4*)&mag[((size_t)srow << 7) + (q << 3) + 4];
    float mv[8] = {m0.x, m0.y, m0.z, m0.w, m1.x, m1.y, m1.z, m1.w};
    short h[8] __attribute__((aligned(16))), m[8] __attribute__((aligned(16))),
          l[8] __attribute__((aligned(16))), z[8] __attribute__((aligned(16)));
#pragma unroll
    for (int e = 0; e < 8; ++e) { split3(mv[e], &h[e], &m[e], &l[e]); z[e] = 0; }
    int off = (row << 7) + (slotf(q, row) << 3);
    *(short8*)&Y[off]         = *(const short8*)h;
    *(short8*)&Y[4096 + off]  = *(const short8*)m;
    *(short8*)&Y[8192 + off]  = *(const short8*)l;
    *(short8*)&Y[12288 + off] = *(const short8*)z;
    *(short8*)&Y[16384 + off] = *(const short8*)z;
    *(short8*)&Y[20480 + off] = *(const short8*)z;
  } else {
    const float* FRb = FRsrc + ((size_t)b << 16);
    // vectorized fused overlap-add -> split3 -> swizzled wfs
    for (int i4 = tid; i4 < 560; i4 += 512) {
      int i = i4 << 2;
      int t = (f0 << 6) + i;
      int ft = t >> 6, cb = t & 63;
      float4 s = make_float4(0.f, 0.f, 0.f, 0.f);
#pragma unroll
      for (int d = 3; d >= 0; --d) {               // ascending f; extras exact 0
        int f = ft - d;
        if (f >= 0 && f <= 255) {
          float4 v = *(const float4*)&FRb[(f << 8) + cb + (d << 6)];
          s.x += v.x; s.y += v.y; s.z += v.z; s.w += v.w;
        }
      }
      if (i == 2236) { s.z = 0.f; s.w = 0.f; }     // pad samples 2238/2239
      short hh[4] __attribute__((aligned(8))), mm[4] __attribute__((aligned(8))),
            ll[4] __attribute__((aligned(8)));
      split3(s.x, &hh[0], &mm[0], &ll[0]);
      split3(s.y, &hh[1], &mm[1], &ll[1]);
      split3(s.z, &hh[2], &mm[2], &ll[2]);
      split3(s.w, &hh[3], &mm[3], &ll[3]);
      int q = i >> 3;
      int qs = (q & ~7) | ((q ^ (q >> 3)) & 7);
      int p = (qs << 3) | (i & 7);
      *(short4v*)&wfsH[p] = *(const short4v*)hh;
      *(short4v*)&wfsM[p] = *(const short4v*)mm;
      *(short4v*)&wfsL[p] = *(const short4v*)ll;
    }

    f32x4 acc1[2][2];
#pragma unroll
    for (int i = 0; i < 2; ++i) { acc1[i][0] = (f32x4){0,0,0,0}; acc1[i][1] = (f32x4){0,0,0,0}; }

    __syncthreads();                               // wfs ready

    // gemm1: X = A(wf) x Wf, K=256, B streamed from L2
    for (int kc = 0; kc < 8; ++kc) {
      short8 Ah[2], Am[2], Al[2];
#pragma unroll
      for (int mt = 0; mt < 2; ++mt) {
        int frame = (mt << 4) + (lane & 15);
        int q = (frame << 3) + (kc << 2) + (lane >> 4);
        int qs = (q & ~7) | ((q ^ (q >> 3)) & 7);
        Ah[mt] = *(const short8*)&wfsH[qs << 3];
        Am[mt] = *(const short8*)&wfsM[qs << 3];
        Al[mt] = *(const short8*)&wfsL[qs << 3];
      }
#pragma unroll
      for (int nt = 0; nt < 2; ++nt) {
        int ntg = (wv << 1) + nt;
        size_t off = (((size_t)((kc << 4) + ntg) << 6) + lane) << 3;
        short8 bh = *(const short8*)(WfH + off);
        short8 bm = *(const short8*)(WfM + off);
        short8 bl = *(const short8*)(WfL + off);
        __builtin_amdgcn_s_setprio(1);             // T5: favor MFMA cluster
#pragma unroll
        for (int mt = 0; mt < 2; ++mt) {
          MFMA6(acc1[mt][nt], Ah[mt], Am[mt], Al[mt], bh, bm, bl)
        }
        __builtin_amdgcn_s_setprio(0);
      }
    }

    // epilogue (tr-bounce): spec = mag*X/|X|; write Sre/Sim
    for (int mtg = 0; mtg < 2; ++mtg) {
      __syncthreads();                             // scratch free
#pragma unroll
      for (int nt = 0; nt < 2; ++nt) {
        int col = (((wv << 1) + nt) << 4) | (lane & 15);
        int cc = col >> 3, hb = (col >> 2) & 1, w = col & 3;
        float* th = hb ? trB : trA;
        int base = (cc << 2) + w;
#pragma unroll
        for (int r = 0; r < 4; ++r) {
          int row16 = ((lane >> 4) << 2) + r;
          th[row16 * 132 + base] = acc1[mtg][nt][r];
        }
      }
      __syncthreads();
      {
        int trow = tid >> 5;                       // 0..15
        int c = tid & 31;                          // 8-col chunk = 4 bins 4c..4c+3
        float4 va = *(const float4*)&trA[trow * 132 + (c << 2)];  // cols 8c+0..3
        float4 vb = *(const float4*)&trB[trow * 132 + (c << 2)];  // cols 8c+4..7
        int lrow = (mtg << 4) + trow;              // 0..31
        int srow = fgl + lrow;
        float4 xm = *(const float4*)&mag[((size_t)srow << 7) + (c << 2)];
        float vv[8] = {va.x, va.y, va.z, va.w, vb.x, vb.y, vb.z, vb.w};
        short reh[4] __attribute__((aligned(8))), rem[4] __attribute__((aligned(8))),
              rel[4] __attribute__((aligned(8))), imh[4] __attribute__((aligned(8))),
              imm[4] __attribute__((aligned(8))), iml[4] __attribute__((aligned(8)));
#pragma unroll
        for (int pq = 0; pq < 4; ++pq) {
          float mg = ((const float*)&xm)[pq];
          float re = vv[2 * pq], im = vv[2 * pq + 1];
          float s2 = re * re + im * im;
          float ore, oim;
          if (s2 == 0.f) { ore = mg; oim = 0.f; }  // angle(0)=0
          else { float rr = mg * rsqrtf(s2); ore = re * rr; oim = im * rr; }
          split3(ore, &reh[pq], &rem[pq], &rel[pq]);
          split3(oim, &imh[pq], &imm[pq], &iml[pq]);
        }
        int c2 = c >> 1, half = (c & 1) << 2;      // bins 4c..4c+3 in [32][128]
        int off2 = (lrow << 7) + (slotf(c2, lrow) << 3) + half;
        *(short4v*)&Y[off2]         = *(const short4v*)reh;
        *(short4v*)&Y[4096 + off2]  = *(const short4v*)rem;
        *(short4v*)&Y[8192 + off2]  = *(const short4v*)rel;
        *(short4v*)&Y[12288 + off2] = *(const short4v*)imh;
        *(short4v*)&Y[16384 + off2] = *(const short4v*)imm;
        *(short4v*)&Y[20480 + off2] = *(const short4v*)iml;
      }
    }
  }

  f32x4 aC[2], aS[2];
#pragma unroll
  for (int i = 0; i < 2; ++i) { aC[i] = (f32x4){0,0,0,0}; aS[i] = (f32x4){0,0,0,0}; }

  __syncthreads();                                 // Sre/Sim ready

  // gemm2 (folded): C = Sre x CI, S_ = Sim x SI, K=128 each
  for (int kc = 0; kc < 4; ++kc) {
    short8 ReH[2], ReM[2], ReL[2], ImH[2], ImM[2], ImL[2];
#pragma unroll
    for (int mt = 0; mt < 2; ++mt) {
      int rl = (mt << 4) + (lane & 15);
      int c = (kc << 2) + (lane >> 4);
      int off = (rl << 7) + (slotf(c, rl) << 3);
      ReH[mt] = *(const short8*)&Y[off];
      ReM[mt] = *(const short8*)&Y[4096 + off];
      ReL[mt] = *(const short8*)&Y[8192 + off];
      ImH[mt] = *(const short8*)&Y[12288 + off];
      ImM[mt] = *(const short8*)&Y[16384 + off];
      ImL[mt] = *(const short8*)&Y[20480 + off];
    }
    size_t flat = (((size_t)((kc << 3) + wv) << 6) + lane) << 3;
    short8 ch = *(const short8*)(CI + flat);
    short8 cm = *(const short8*)(CI + 16384 + flat);
    short8 cl = *(const short8*)(CI + 32768 + flat);
    short8 sh = *(const short8*)(SI + flat);
    short8 sm = *(const short8*)(SI + 16384 + flat);
    short8 sl = *(const short8*)(SI + 32768 + flat);
    __builtin_amdgcn_s_setprio(1);                 // T5
#pragma unroll
    for (int mt = 0; mt < 2; ++mt) {
      MFMA6(aC[mt], ReH[mt], ReM[mt], ReL[mt], ch, cm, cl)
      MFMA6(aS[mt], ImH[mt], ImM[mt], ImL[mt], sh, sm, sl)
    }
    __builtin_amdgcn_s_setprio(0);
  }

  // unfold: fr[n]=swin[n](C+S_), fr[254-n]=swin[254-n](C-S_)
  {
    int n = (wv << 4) + (lane & 15);               // 0..127
    float swn = swin[n];
    float swp = swin[254 - n];
    float* FRo = FRdst + ((size_t)b << 16) + ((size_t)f0 << 8);
#pragma unroll
    for (int mt = 0; mt < 2; ++mt)
#pragma unroll
      for (int r = 0; r < 4; ++r) {
        int row = (mt << 4) + ((lane >> 4) << 2) + r;
        float C = aC[mt][r], S_ = aS[mt][r];
        FRo[((size_t)row << 8) + n] = swn * (C + S_);
        if (n >= 1 && n <= 126) FRo[((size_t)row << 8) + 254 - n] = swp * (C - S_);
        if (n == 0) { FRo[((size_t)row << 8) + 254] = 0.f; FRo[((size_t)row << 8) + 255] = 0.f; }
      }
  }
}

// ------------------------------------------------- reductions (OA fused) ----
__global__ void redmax_k(const float* __restrict__ FR, unsigned* __restrict__ gmax) {
  __shared__ float red[16];
  int b = blockIdx.x;
  const float* FRb = FR + ((size_t)b << 16);
  float v = 0.f;
  for (int t = threadIdx.x; t < OUTL; t += 1024) {
    int f_hi = t >> 6; if (f_hi > NFRM - 1) f_hi = NFRM - 1;
    int f_lo = (t >= NFFT) ? (((t - NFFT) >> 6) + 1) : 0;
    float s = 0.f;
    for (int f = f_lo; f <= f_hi; ++f) s += FRb[(f << 8) + t - (f << 6)];
    v = fmaxf(v, fabsf(s));
  }
#pragma unroll
  for (int o = 32; o > 0; o >>= 1) v = fmaxf(v, __shfl_xor(v, o, 64));
  if ((threadIdx.x & 63) == 0) red[threadIdx.x >> 6] = v;
  __syncthreads();
  if (threadIdx.x < 16) {
    v = red[threadIdx.x];
#pragma unroll
    for (int o = 8; o > 0; o >>= 1) v = fmaxf(v, __shfl_xor(v, o, 16));
    if (threadIdx.x == 0) atomicMax(gmax, __float_as_uint(v));
  }
}

__global__ void out_k(const float* __restrict__ FR, const unsigned* __restrict__ gmax,
                      float* __restrict__ out) {
  int b = blockIdx.y, t = blockIdx.x * 256 + threadIdx.x;   // t < 16384
  const float* FRb = FR + ((size_t)b << 16);
  int f_hi = t >> 6; if (f_hi > NFRM - 1) f_hi = NFRM - 1;
  int f_lo = (t >= NFFT) ? (((t - NFFT) >> 6) + 1) : 0;
  float s = 0.f;
  for (int f = f_lo; f <= f_hi; ++f) s += FRb[(f << 8) + t - (f << 6)];
  float g = __uint_as_float(*gmax);
  out[(size_t)b * AUD + t] = s / g;
}

// ---------------------------------------------------------------- launch ----
extern "C" void kernel_launch(void* const* d_in, const int* in_sizes, int n_in,
                              void* d_out, int out_size, void* d_ws, size_t ws_size,
                              hipStream_t stream) {
  const float* x = (const float*)d_in[0];

  float* FR0 = (float*)d_ws;                       // 8,388,608 f
  float* FR1 = FR0 + 8388608;                      // 8,388,608 f
  float* mag = FR1 + 8388608;                      // 4,194,304 f
  short* WfH = (short*)(mag + 4194304);            // 65536 sh each
  short* WfM = WfH + 65536;
  short* WfL = WfM + 65536;
  short* CI  = WfL + 65536;                        // 49152 sh each
  short* SI  = CI + 49152;
  float* swin = (float*)(SI + 49152);              // 256 f
  unsigned* gmax = (unsigned*)(swin + 256);        // ~84.7 MB total

  mag_k<<<16384, 256, 0, stream>>>(x, mag);
  tables_k<<<256, 256, 0, stream>>>(WfH, WfM, WfL, CI, SI, swin, gmax);

  // initial istft of (mag, 0) -> FR0
  iter_k<1><<<1024, 512, 0, stream>>>(FR1, FR0, mag, swin, WfH, WfM, WfL, CI, SI);

  float* bufs[2] = {FR0, FR1};
  for (int it = 0; it < GL_ITERS; ++it) {
    iter_k<0><<<1024, 512, 0, stream>>>(bufs[it & 1], bufs[(it + 1) & 1], mag, swin,
                                        WfH, WfM, WfL, CI, SI);
  }
  // 50 even -> final waveform frames in FR0

  redmax_k<<<B_SZ, 1024, 0, stream>>>(FR0, gmax);
  out_k<<<dim3(64, B_SZ), 256, 0, stream>>>(FR0, gmax, (float*)d_out);
}